// Round 1
// baseline (101.753 us; speedup 1.0000x reference)
//
#include <hip/hip_runtime.h>
#include <math.h>

#define HH 384
#define WW 640
#define HWSZ (HH*WW)
#define BB 2
#define NN 6
#define BPG 64   // blocks per (warp,batch) group in phaseA

// ws layout (floats):
//  [0..143]    P matrices: (w*BB+b)*12  (3x4 row-major)
//  [144..161]  invK3 per b: 144 + b*9
//  [176..182]  cams (ints): cams[0..5] = src cam per warp, cams[6] = ref cam
//  [192..287]  accumulators: 192 + (w*BB+b)*8 + k   k: cnt, s_masked, w_masked, w_sum, w_sumsq, s_sum, s_sumsq
//  [288..359]  stats: 288 + (w*BB+b)*6 : s_mean, s_std, w_mean, w_std, any_zero
#define WS_P    0
#define WS_INVK 144
#define WS_CAM  176
#define WS_ACC  192
#define WS_STAT 288

// ---- projection, f32 op-order mirrored to the JAX reference, no FMA contraction ----
__device__ __forceinline__ void project_pix(const float* __restrict__ Pm, const float* __restrict__ ik,
                                            float fx, float fy, float d,
                                            float& gx, float& gy, float& sx, float& sy)
{
    // q = invK3 @ (fx, fy, 1)   (einsum, j ascending)
    float q0 = __fadd_rn(__fadd_rn(__fmul_rn(ik[0], fx), __fmul_rn(ik[1], fy)), ik[2]);
    float q1 = __fadd_rn(__fadd_rn(__fmul_rn(ik[3], fx), __fmul_rn(ik[4], fy)), ik[5]);
    float q2 = __fadd_rn(__fadd_rn(__fmul_rn(ik[6], fx), __fmul_rn(ik[7], fy)), ik[8]);
    // p3 = q * d
    float a0 = __fmul_rn(q0, d), a1 = __fmul_rn(q1, d), a2 = __fmul_rn(q2, d);
    // p2 = P[:3,:4] @ [p3; 1]
    float p0 = __fadd_rn(__fadd_rn(__fadd_rn(__fmul_rn(Pm[0], a0), __fmul_rn(Pm[1], a1)), __fmul_rn(Pm[2], a2)), Pm[3]);
    float p1 = __fadd_rn(__fadd_rn(__fadd_rn(__fmul_rn(Pm[4], a0), __fmul_rn(Pm[5], a1)), __fmul_rn(Pm[6], a2)), Pm[7]);
    float p2 = __fadd_rn(__fadd_rn(__fadd_rn(__fmul_rn(Pm[8], a0), __fmul_rn(Pm[9], a1)), __fmul_rn(Pm[10], a2)), Pm[11]);
    float z  = __fadd_rn(p2, 1e-7f);
    float xx = __fdiv_rn(p0, z);
    float yy = __fdiv_rn(p1, z);
    // pix = (xy / [W-1,H-1] - 0.5) * 2
    gx = __fmul_rn(__fsub_rn(__fdiv_rn(xx, 639.0f), 0.5f), 2.0f);
    gy = __fmul_rn(__fsub_rn(__fdiv_rn(yy, 383.0f), 0.5f), 2.0f);
    // grid_sample: x = ((pix+1)*0.5)*(W-1)
    sx = __fmul_rn(__fmul_rn(__fadd_rn(gx, 1.0f), 0.5f), 639.0f);
    sy = __fmul_rn(__fmul_rn(__fadd_rn(gy, 1.0f), 0.5f), 383.0f);
}

__device__ __forceinline__ void sample_one(const float* __restrict__ simg, const float* __restrict__ smask,
                                           const float* Pm, const float* ik, float d, int px_i, int py_i,
                                           float& i0, float& i1, float& i2, float& wmv)
{
    float gx, gy, sx, sy;
    project_pix(Pm, ik, (float)px_i, (float)py_i, d, gx, gy, sx, sy);

    // bilinear with zero padding
    float x0f = floorf(sx), y0f = floorf(sy);
    float wx = __fsub_rn(sx, x0f), wy = __fsub_rn(sy, y0f);
    int x0 = (int)x0f, y0 = (int)y0f;
    int x1 = x0 + 1, y1 = y0 + 1;
    bool vx0 = (x0 >= 0) && (x0 < WW), vx1 = (x1 >= 0) && (x1 < WW);
    bool vy0 = (y0 >= 0) && (y0 < HH), vy1 = (y1 >= 0) && (y1 < HH);
    int cx0 = min(max(x0, 0), WW - 1), cx1 = min(max(x1, 0), WW - 1);
    int cy0 = min(max(y0, 0), HH - 1), cy1 = min(max(y1, 0), HH - 1);
    float w00 = (1.0f - wx) * (1.0f - wy);
    float w01 = wx * (1.0f - wy);
    float w10 = (1.0f - wx) * wy;
    float w11 = wx * wy;
    float f00 = (vy0 && vx0) ? 1.0f : 0.0f;
    float f01 = (vy0 && vx1) ? 1.0f : 0.0f;
    float f10 = (vy1 && vx0) ? 1.0f : 0.0f;
    float f11 = (vy1 && vx1) ? 1.0f : 0.0f;
    int o00 = cy0 * WW + cx0, o01 = cy0 * WW + cx1;
    int o10 = cy1 * WW + cx0, o11 = cy1 * WW + cx1;
    float res[3];
#pragma unroll
    for (int c = 0; c < 3; c++) {
        const float* ch = simg + (size_t)c * HWSZ;
        float v00 = ch[o00] * f00, v01 = ch[o01] * f01;
        float v10 = ch[o10] * f10, v11 = ch[o11] * f11;
        float v = ((v00 * w00 + v01 * w01) + v10 * w10) + v11 * w11;
        res[c] = (v != v) ? 2.0f : v;   // nan -> 2.0
    }
    // nearest mask sample (round half to even, matching jnp.round)
    float xr = rintf(sx), yr = rintf(sy);
    int xi = (int)xr, yi = (int)yr;
    bool vm = (xi >= 0) && (xi < WW) && (yi >= 0) && (yi < HH);
    float mv = smask[min(max(yi, 0), HH - 1) * WW + min(max(xi, 0), WW - 1)] * (vm ? 1.0f : 0.0f);
    if (mv != mv) mv = 0.0f;            // nan -> 0
    bool invalid = (gx > 1.0f) || (gx < -1.0f) || (gy > 1.0f) || (gy < -1.0f);
    wmv = invalid ? 0.0f : mv;
    i0 = res[0]; i1 = res[1]; i2 = res[2];
}

__global__ void vr_setup(const float* __restrict__ K, const float* __restrict__ invK,
                         const float* __restrict__ p2c, const float* __restrict__ c2n,
                         const float* __restrict__ rel, const void* __restrict__ camI,
                         const void* __restrict__ nbr, float* __restrict__ ws)
{
    int tid = threadIdx.x;
    if (tid < 96) ws[WS_ACC + tid] = 0.0f;   // re-zero accumulators every call
    if (tid == 0) {
        int ci = ((const int*)camI)[0];
        // neighbor indices: robust against int64 vs int32 storage
        long long a = ((const long long*)nbr)[0];
        long long bq = ((const long long*)nbr)[1];
        int n0, n1;
        if (a >= 0 && a < NN && bq >= 0 && bq < NN) { n0 = (int)a; n1 = (int)bq; }
        else { n0 = ((const int*)nbr)[0]; n1 = ((const int*)nbr)[1]; }
        int* cams = (int*)(ws + WS_CAM);
        cams[0] = ci; cams[1] = ci; cams[2] = n0; cams[3] = n1; cams[4] = n0; cams[5] = n1;
        cams[6] = ci;
        for (int b = 0; b < BB; b++) {
            const float* ik = invK + (size_t)(b * NN + ci) * 16;
            float* dst = ws + WS_INVK + b * 9;
            dst[0] = ik[0]; dst[1] = ik[1]; dst[2] = ik[2];
            dst[3] = ik[4]; dst[4] = ik[5]; dst[5] = ik[6];
            dst[6] = ik[8]; dst[7] = ik[9]; dst[8] = ik[10];
            for (int w = 0; w < 6; w++) {
                int cam = cams[w];
                const float* Km = K + (size_t)(b * NN + cam) * 16;
                const float* T;
                if (w == 0)      T = p2c + (size_t)(b * NN + ci) * 16;
                else if (w == 1) T = c2n + (size_t)(b * NN + ci) * 16;
                else {
                    int f = (w >= 4) ? 1 : 0;
                    int n = (w == 3 || w == 5) ? 1 : 0;
                    T = rel + (size_t)((f * 2 + n) * BB + b) * 16;
                }
                float* Pd = ws + WS_P + (w * BB + b) * 12;
                for (int i = 0; i < 3; i++)
                    for (int j = 0; j < 4; j++) {
                        float s = __fadd_rn(__fadd_rn(__fadd_rn(
                                      __fmul_rn(Km[i * 4 + 0], T[0 * 4 + j]),
                                      __fmul_rn(Km[i * 4 + 1], T[1 * 4 + j])),
                                      __fmul_rn(Km[i * 4 + 2], T[2 * 4 + j])),
                                      __fmul_rn(Km[i * 4 + 3], T[3 * 4 + j]));
                        Pd[i * 4 + j] = s;
                    }
            }
        }
    }
}

__global__ __launch_bounds__(256) void vr_phaseA(
    const float* __restrict__ prev, const float* __restrict__ nxt,
    const float* __restrict__ org, const float* __restrict__ maskT,
    const float* __restrict__ depthT, float* __restrict__ ws)
{
    int group = blockIdx.x / BPG;     // 12 groups = (w, b)
    int blkin = blockIdx.x % BPG;
    int w = group / BB, b = group % BB;
    const int* cams = (const int*)(ws + WS_CAM);
    int ci = cams[6];
    int cam = cams[w];
    float Pl[12], ikl[9];
    {
        const float* Pm = ws + WS_P + group * 12;
        const float* ik = ws + WS_INVK + b * 9;
#pragma unroll
        for (int i = 0; i < 12; i++) Pl[i] = Pm[i];
#pragma unroll
        for (int i = 0; i < 9; i++) ikl[i] = ik[i];
    }
    const float* simg  = ((w == 0 || w == 2 || w == 3) ? prev : nxt) + (size_t)(b * NN + cam) * 3 * HWSZ;
    const float* smask = maskT + (size_t)(b * NN + cam) * HWSZ;
    const float* dep   = depthT + (size_t)(b * NN + ci) * HWSZ;
    const float* rimg  = org + (size_t)(b * NN + ci) * 3 * HWSZ;
    const float* rmask = maskT + (size_t)(b * NN + ci) * HWSZ;

    float acc[7] = {0, 0, 0, 0, 0, 0, 0};
    for (int p = blkin * 256 + threadIdx.x; p < HWSZ; p += BPG * 256) {
        int py_i = p / WW, px_i = p - py_i * WW;
        float d = dep[p];
        float i0, i1, i2, wmv;
        sample_one(simg, smask, Pl, ikl, d, px_i, py_i, i0, i1, i2, wmv);
        float rm = rmask[p];
        float m = (rm * wmv > 0.0f) ? 1.0f : 0.0f;
        float r0 = rimg[p], r1 = rimg[HWSZ + p], r2 = rimg[2 * HWSZ + p];
        float ws3 = i0 + i1 + i2;
        float rs3 = r0 + r1 + r2;
        acc[0] += m;
        acc[1] += rs3 * m;
        acc[2] += ws3 * m;
        acc[3] += ws3;
        acc[4] += i0 * i0 + i1 * i1 + i2 * i2;
        acc[5] += rs3;
        acc[6] += r0 * r0 + r1 * r1 + r2 * r2;
    }
    __shared__ float sred[4][7];
    int lane = threadIdx.x & 63, wv = threadIdx.x >> 6;
#pragma unroll
    for (int k = 0; k < 7; k++) {
        float v = acc[k];
        for (int off = 32; off; off >>= 1) v += __shfl_down(v, off);
        if (lane == 0) sred[wv][k] = v;
    }
    __syncthreads();
    if (threadIdx.x < 7) {
        float s = sred[0][threadIdx.x] + sred[1][threadIdx.x] + sred[2][threadIdx.x] + sred[3][threadIdx.x];
        atomicAdd(&ws[WS_ACC + group * 8 + threadIdx.x], s);
    }
}

__global__ void vr_finalize(float* __restrict__ ws)
{
    int t = threadIdx.x;
    if (t >= 12) return;
    int w = t / BB;
    const float* acc = ws + WS_ACC + t * 8;
    double cnt = acc[0], smask = acc[1], wmask = acc[2];
    double wsum = acc[3], wsumsq = acc[4], ssum = acc[5], ssumsq = acc[6];
    double msum = 3.0 * cnt;
    double NT = 3.0 * (double)HWSZ;
    double smean = smask / (msum + 1e-8);
    double svar  = (ssumsq - 2.0 * smean * ssum + NT * smean * smean) / NT;
    double sstd  = sqrt(svar + 1e-16);
    double wmean = wmask / (msum + 1e-8);
    double wvar  = (wsumsq - 2.0 * wmean * wsum + NT * wmean * wmean) / NT;
    double wstd  = sqrt(wvar + 1e-16);
    float cnt0 = ws[WS_ACC + (w * BB + 0) * 8];
    float cnt1 = ws[WS_ACC + (w * BB + 1) * 8];
    float az = (cnt0 == 0.0f || cnt1 == 0.0f) ? 1.0f : 0.0f;
    float* st = ws + WS_STAT + t * 6;
    st[0] = (float)smean; st[1] = (float)sstd;
    st[2] = (float)wmean; st[3] = (float)wstd;
    st[4] = az;
}

__global__ __launch_bounds__(256) void vr_phaseB(
    const float* __restrict__ prev, const float* __restrict__ nxt,
    const float* __restrict__ maskT, const float* __restrict__ depthT,
    const float* __restrict__ ws, float* __restrict__ out)
{
    int idx = blockIdx.x * 256 + threadIdx.x;
    int ob = idx / (BB * HWSZ);
    int rem = idx - ob * (BB * HWSZ);
    int b = rem / HWSZ;
    int p = rem - b * HWSZ;
    const int* cams = (const int*)(ws + WS_CAM);
    int ci = cams[6];
    float d = depthT[(size_t)(b * NN + ci) * HWSZ + p];
    int py_i = p / WW, px_i = p - py_i * WW;
    int w0 = (ob == 0) ? 0 : (ob == 1) ? 1 : (ob == 2) ? 2 : 4;
    int nw = (ob < 2) ? 1 : 2;
    float o0 = 0, o1 = 0, o2 = 0, om = 0;
    for (int k = 0; k < nw; k++) {
        int w = w0 + k;
        int cam = cams[w];
        int group = w * BB + b;
        const float* Pm = ws + WS_P + group * 12;
        const float* ik = ws + WS_INVK + b * 9;
        const float* simg  = ((w == 0 || w == 2 || w == 3) ? prev : nxt) + (size_t)(b * NN + cam) * 3 * HWSZ;
        const float* smask = maskT + (size_t)(b * NN + cam) * HWSZ;
        float i0, i1, i2, wmv;
        sample_one(simg, smask, Pm, ik, d, px_i, py_i, i0, i1, i2, wmv);
        const float* st = ws + WS_STAT + group * 6;
        float smean = st[0], sstd = st[1], wmean = st[2], wstd = st[3];
        bool az = st[4] != 0.0f;
        float v0, v1, v2;
        if (az) { v0 = i0; v1 = i1; v2 = i2; }
        else {
            v0 = ((i0 - wmean) / (wstd + 1e-8f)) * sstd + smean; v0 *= wmv;
            v1 = ((i1 - wmean) / (wstd + 1e-8f)) * sstd + smean; v1 *= wmv;
            v2 = ((i2 - wmean) / (wstd + 1e-8f)) * sstd + smean; v2 *= wmv;
        }
        o0 += v0; o1 += v1; o2 += v2; om += wmv;
    }
    float* base = out + ((size_t)b * 16 + ob * 4) * HWSZ;
    base[p] = o0;
    base[HWSZ + p] = o1;
    base[2 * HWSZ + p] = o2;
    base[3 * HWSZ + p] = om;
}

extern "C" void kernel_launch(void* const* d_in, const int* in_sizes, int n_in,
                              void* d_out, int out_size, void* d_ws, size_t ws_size,
                              hipStream_t stream)
{
    const float* prev  = (const float*)d_in[0];
    const float* org   = (const float*)d_in[1];
    const float* nxt   = (const float*)d_in[2];
    const float* maskT = (const float*)d_in[3];
    const float* K     = (const float*)d_in[4];
    const float* invK  = (const float*)d_in[5];
    const float* dep   = (const float*)d_in[6];
    const float* p2c   = (const float*)d_in[7];
    const float* c2n   = (const float*)d_in[8];
    const float* rel   = (const float*)d_in[9];
    const void*  camI  = d_in[10];
    const void*  nbr   = d_in[11];
    float* ws  = (float*)d_ws;
    float* out = (float*)d_out;

    hipLaunchKernelGGL(vr_setup, dim3(1), dim3(128), 0, stream, K, invK, p2c, c2n, rel, camI, nbr, ws);
    hipLaunchKernelGGL(vr_phaseA, dim3(12 * BPG), dim3(256), 0, stream, prev, nxt, org, maskT, dep, ws);
    hipLaunchKernelGGL(vr_finalize, dim3(1), dim3(64), 0, stream, ws);
    hipLaunchKernelGGL(vr_phaseB, dim3(4 * BB * HWSZ / 256), dim3(256), 0, stream, prev, nxt, maskT, dep, ws, out);
}

// Round 2
// 78.474 us; speedup vs baseline: 1.2967x; 1.2967x over previous
//
#include <hip/hip_runtime.h>
#include <math.h>

#define HH 384
#define WW 640
#define HWSZ (HH*WW)
#define BB 2
#define NN 6
#define BPG 256   // blocks per (warp,batch) group in phaseA

// ws layout (floats):
//  [0..143]    P matrices: (w*BB+b)*12  (3x4 row-major)
//  [144..161]  invK3 per b: 144 + b*9
//  [176..182]  cams (ints): cams[0..5] = src cam per warp, cams[6] = ref cam
//  [192..287]  accumulators: 192 + (w*BB+b)*8 + k
//  [288..359]  stats: 288 + (w*BB+b)*6
//  [512..]     sample cache: (group*4 + c)*HWSZ + p   (12 groups x 4 planes)
#define WS_P     0
#define WS_INVK  144
#define WS_CAM   176
#define WS_ACC   192
#define WS_STAT  288
#define WS_CACHE 512

// ---- projection, f32 op-order mirrored to the JAX reference, no FMA contraction ----
__device__ __forceinline__ void project_pix(const float* __restrict__ Pm, const float* __restrict__ ik,
                                            float fx, float fy, float d,
                                            float& gx, float& gy, float& sx, float& sy)
{
    float q0 = __fadd_rn(__fadd_rn(__fmul_rn(ik[0], fx), __fmul_rn(ik[1], fy)), ik[2]);
    float q1 = __fadd_rn(__fadd_rn(__fmul_rn(ik[3], fx), __fmul_rn(ik[4], fy)), ik[5]);
    float q2 = __fadd_rn(__fadd_rn(__fmul_rn(ik[6], fx), __fmul_rn(ik[7], fy)), ik[8]);
    float a0 = __fmul_rn(q0, d), a1 = __fmul_rn(q1, d), a2 = __fmul_rn(q2, d);
    float p0 = __fadd_rn(__fadd_rn(__fadd_rn(__fmul_rn(Pm[0], a0), __fmul_rn(Pm[1], a1)), __fmul_rn(Pm[2], a2)), Pm[3]);
    float p1 = __fadd_rn(__fadd_rn(__fadd_rn(__fmul_rn(Pm[4], a0), __fmul_rn(Pm[5], a1)), __fmul_rn(Pm[6], a2)), Pm[7]);
    float p2 = __fadd_rn(__fadd_rn(__fadd_rn(__fmul_rn(Pm[8], a0), __fmul_rn(Pm[9], a1)), __fmul_rn(Pm[10], a2)), Pm[11]);
    float z  = __fadd_rn(p2, 1e-7f);
    float xx = __fdiv_rn(p0, z);
    float yy = __fdiv_rn(p1, z);
    gx = __fmul_rn(__fsub_rn(__fdiv_rn(xx, 639.0f), 0.5f), 2.0f);
    gy = __fmul_rn(__fsub_rn(__fdiv_rn(yy, 383.0f), 0.5f), 2.0f);
    sx = __fmul_rn(__fmul_rn(__fadd_rn(gx, 1.0f), 0.5f), 639.0f);
    sy = __fmul_rn(__fmul_rn(__fadd_rn(gy, 1.0f), 0.5f), 383.0f);
}

__device__ __forceinline__ void sample_one(const float* __restrict__ simg, const float* __restrict__ smask,
                                           const float* Pm, const float* ik, float d, int px_i, int py_i,
                                           float& i0, float& i1, float& i2, float& wmv)
{
    float gx, gy, sx, sy;
    project_pix(Pm, ik, (float)px_i, (float)py_i, d, gx, gy, sx, sy);

    float x0f = floorf(sx), y0f = floorf(sy);
    float wx = __fsub_rn(sx, x0f), wy = __fsub_rn(sy, y0f);
    int x0 = (int)x0f, y0 = (int)y0f;
    int x1 = x0 + 1, y1 = y0 + 1;
    bool vx0 = (x0 >= 0) && (x0 < WW), vx1 = (x1 >= 0) && (x1 < WW);
    bool vy0 = (y0 >= 0) && (y0 < HH), vy1 = (y1 >= 0) && (y1 < HH);
    int cx0 = min(max(x0, 0), WW - 1), cx1 = min(max(x1, 0), WW - 1);
    int cy0 = min(max(y0, 0), HH - 1), cy1 = min(max(y1, 0), HH - 1);
    float w00 = (1.0f - wx) * (1.0f - wy);
    float w01 = wx * (1.0f - wy);
    float w10 = (1.0f - wx) * wy;
    float w11 = wx * wy;
    float f00 = (vy0 && vx0) ? 1.0f : 0.0f;
    float f01 = (vy0 && vx1) ? 1.0f : 0.0f;
    float f10 = (vy1 && vx0) ? 1.0f : 0.0f;
    float f11 = (vy1 && vx1) ? 1.0f : 0.0f;
    int o00 = cy0 * WW + cx0, o01 = cy0 * WW + cx1;
    int o10 = cy1 * WW + cx0, o11 = cy1 * WW + cx1;
    float res[3];
#pragma unroll
    for (int c = 0; c < 3; c++) {
        const float* ch = simg + (size_t)c * HWSZ;
        float v00 = ch[o00] * f00, v01 = ch[o01] * f01;
        float v10 = ch[o10] * f10, v11 = ch[o11] * f11;
        float v = ((v00 * w00 + v01 * w01) + v10 * w10) + v11 * w11;
        res[c] = (v != v) ? 2.0f : v;
    }
    float xr = rintf(sx), yr = rintf(sy);
    int xi = (int)xr, yi = (int)yr;
    bool vm = (xi >= 0) && (xi < WW) && (yi >= 0) && (yi < HH);
    float mv = smask[min(max(yi, 0), HH - 1) * WW + min(max(xi, 0), WW - 1)] * (vm ? 1.0f : 0.0f);
    if (mv != mv) mv = 0.0f;
    bool invalid = (gx > 1.0f) || (gx < -1.0f) || (gy > 1.0f) || (gy < -1.0f);
    wmv = invalid ? 0.0f : mv;
    i0 = res[0]; i1 = res[1]; i2 = res[2];
}

__global__ void vr_setup(const float* __restrict__ K, const float* __restrict__ invK,
                         const float* __restrict__ p2c, const float* __restrict__ c2n,
                         const float* __restrict__ rel, const void* __restrict__ camI,
                         const void* __restrict__ nbr, float* __restrict__ ws)
{
    int tid = threadIdx.x;
    if (tid < 96) ws[WS_ACC + tid] = 0.0f;
    if (tid == 0) {
        int ci = ((const int*)camI)[0];
        long long a = ((const long long*)nbr)[0];
        long long bq = ((const long long*)nbr)[1];
        int n0, n1;
        if (a >= 0 && a < NN && bq >= 0 && bq < NN) { n0 = (int)a; n1 = (int)bq; }
        else { n0 = ((const int*)nbr)[0]; n1 = ((const int*)nbr)[1]; }
        int* cams = (int*)(ws + WS_CAM);
        cams[0] = ci; cams[1] = ci; cams[2] = n0; cams[3] = n1; cams[4] = n0; cams[5] = n1;
        cams[6] = ci;
        for (int b = 0; b < BB; b++) {
            const float* ik = invK + (size_t)(b * NN + ci) * 16;
            float* dst = ws + WS_INVK + b * 9;
            dst[0] = ik[0]; dst[1] = ik[1]; dst[2] = ik[2];
            dst[3] = ik[4]; dst[4] = ik[5]; dst[5] = ik[6];
            dst[6] = ik[8]; dst[7] = ik[9]; dst[8] = ik[10];
            for (int w = 0; w < 6; w++) {
                int cam = cams[w];
                const float* Km = K + (size_t)(b * NN + cam) * 16;
                const float* T;
                if (w == 0)      T = p2c + (size_t)(b * NN + ci) * 16;
                else if (w == 1) T = c2n + (size_t)(b * NN + ci) * 16;
                else {
                    int f = (w >= 4) ? 1 : 0;
                    int n = (w == 3 || w == 5) ? 1 : 0;
                    T = rel + (size_t)((f * 2 + n) * BB + b) * 16;
                }
                float* Pd = ws + WS_P + (w * BB + b) * 12;
                for (int i = 0; i < 3; i++)
                    for (int j = 0; j < 4; j++) {
                        float s = __fadd_rn(__fadd_rn(__fadd_rn(
                                      __fmul_rn(Km[i * 4 + 0], T[0 * 4 + j]),
                                      __fmul_rn(Km[i * 4 + 1], T[1 * 4 + j])),
                                      __fmul_rn(Km[i * 4 + 2], T[2 * 4 + j])),
                                      __fmul_rn(Km[i * 4 + 3], T[3 * 4 + j]));
                        Pd[i * 4 + j] = s;
                    }
            }
        }
    }
}

__global__ __launch_bounds__(256) void vr_phaseA(
    const float* __restrict__ prev, const float* __restrict__ nxt,
    const float* __restrict__ org, const float* __restrict__ maskT,
    const float* __restrict__ depthT, float* __restrict__ ws, int use_cache)
{
    int group = blockIdx.x / BPG;     // 12 groups = (w, b)
    int blkin = blockIdx.x % BPG;
    int w = group / BB, b = group % BB;
    const int* cams = (const int*)(ws + WS_CAM);
    int ci = cams[6];
    int cam = cams[w];
    float Pl[12], ikl[9];
    {
        const float* Pm = ws + WS_P + group * 12;
        const float* ik = ws + WS_INVK + b * 9;
#pragma unroll
        for (int i = 0; i < 12; i++) Pl[i] = Pm[i];
#pragma unroll
        for (int i = 0; i < 9; i++) ikl[i] = ik[i];
    }
    const float* simg  = ((w == 0 || w == 2 || w == 3) ? prev : nxt) + (size_t)(b * NN + cam) * 3 * HWSZ;
    const float* smask = maskT + (size_t)(b * NN + cam) * HWSZ;
    const float* dep   = depthT + (size_t)(b * NN + ci) * HWSZ;
    const float* rimg  = org + (size_t)(b * NN + ci) * 3 * HWSZ;
    const float* rmask = maskT + (size_t)(b * NN + ci) * HWSZ;
    float* cache = ws + WS_CACHE + (size_t)group * 4 * HWSZ;

    float acc[7] = {0, 0, 0, 0, 0, 0, 0};
    for (int p = blkin * 256 + threadIdx.x; p < HWSZ; p += BPG * 256) {
        int py_i = p / WW, px_i = p - py_i * WW;
        float d = dep[p];
        float i0, i1, i2, wmv;
        sample_one(simg, smask, Pl, ikl, d, px_i, py_i, i0, i1, i2, wmv);
        if (use_cache) {
            cache[p] = i0;
            cache[HWSZ + p] = i1;
            cache[2 * HWSZ + p] = i2;
            cache[3 * HWSZ + p] = wmv;
        }
        float rm = rmask[p];
        float m = (rm * wmv > 0.0f) ? 1.0f : 0.0f;
        float r0 = rimg[p], r1 = rimg[HWSZ + p], r2 = rimg[2 * HWSZ + p];
        float ws3 = i0 + i1 + i2;
        float rs3 = r0 + r1 + r2;
        acc[0] += m;
        acc[1] += rs3 * m;
        acc[2] += ws3 * m;
        acc[3] += ws3;
        acc[4] += i0 * i0 + i1 * i1 + i2 * i2;
        acc[5] += rs3;
        acc[6] += r0 * r0 + r1 * r1 + r2 * r2;
    }
    __shared__ float sred[4][7];
    int lane = threadIdx.x & 63, wv = threadIdx.x >> 6;
#pragma unroll
    for (int k = 0; k < 7; k++) {
        float v = acc[k];
        for (int off = 32; off; off >>= 1) v += __shfl_down(v, off);
        if (lane == 0) sred[wv][k] = v;
    }
    __syncthreads();
    if (threadIdx.x < 7) {
        float s = sred[0][threadIdx.x] + sred[1][threadIdx.x] + sred[2][threadIdx.x] + sred[3][threadIdx.x];
        atomicAdd(&ws[WS_ACC + group * 8 + threadIdx.x], s);
    }
}

__global__ void vr_finalize(float* __restrict__ ws)
{
    int t = threadIdx.x;
    if (t >= 12) return;
    int w = t / BB;
    const float* acc = ws + WS_ACC + t * 8;
    double cnt = acc[0], smask = acc[1], wmask = acc[2];
    double wsum = acc[3], wsumsq = acc[4], ssum = acc[5], ssumsq = acc[6];
    double msum = 3.0 * cnt;
    double NT = 3.0 * (double)HWSZ;
    double smean = smask / (msum + 1e-8);
    double svar  = (ssumsq - 2.0 * smean * ssum + NT * smean * smean) / NT;
    double sstd  = sqrt(svar + 1e-16);
    double wmean = wmask / (msum + 1e-8);
    double wvar  = (wsumsq - 2.0 * wmean * wsum + NT * wmean * wmean) / NT;
    double wstd  = sqrt(wvar + 1e-16);
    float cnt0 = ws[WS_ACC + (w * BB + 0) * 8];
    float cnt1 = ws[WS_ACC + (w * BB + 1) * 8];
    float az = (cnt0 == 0.0f || cnt1 == 0.0f) ? 1.0f : 0.0f;
    float* st = ws + WS_STAT + t * 6;
    st[0] = (float)smean; st[1] = (float)sstd;
    st[2] = (float)wmean; st[3] = (float)wstd;
    st[4] = az;
}

__global__ __launch_bounds__(256) void vr_phaseB(
    const float* __restrict__ prev, const float* __restrict__ nxt,
    const float* __restrict__ maskT, const float* __restrict__ depthT,
    const float* __restrict__ ws, float* __restrict__ out, int use_cache)
{
    int idx = blockIdx.x * 256 + threadIdx.x;
    int ob = idx / (BB * HWSZ);
    int rem = idx - ob * (BB * HWSZ);
    int b = rem / HWSZ;
    int p = rem - b * HWSZ;
    const int* cams = (const int*)(ws + WS_CAM);
    int ci = cams[6];
    int py_i = p / WW, px_i = p - py_i * WW;
    int w0 = (ob == 0) ? 0 : (ob == 1) ? 1 : (ob == 2) ? 2 : 4;
    int nw = (ob < 2) ? 1 : 2;
    float o0 = 0, o1 = 0, o2 = 0, om = 0;
    for (int k = 0; k < nw; k++) {
        int w = w0 + k;
        int group = w * BB + b;
        float i0, i1, i2, wmv;
        if (use_cache) {
            const float* cg = ws + WS_CACHE + (size_t)group * 4 * HWSZ;
            i0 = cg[p]; i1 = cg[HWSZ + p]; i2 = cg[2 * HWSZ + p]; wmv = cg[3 * HWSZ + p];
        } else {
            int cam = cams[w];
            const float* Pm = ws + WS_P + group * 12;
            const float* ik = ws + WS_INVK + b * 9;
            const float* simg  = ((w == 0 || w == 2 || w == 3) ? prev : nxt) + (size_t)(b * NN + cam) * 3 * HWSZ;
            const float* smask = maskT + (size_t)(b * NN + cam) * HWSZ;
            float d = depthT[(size_t)(b * NN + ci) * HWSZ + p];
            sample_one(simg, smask, Pm, ik, d, px_i, py_i, i0, i1, i2, wmv);
        }
        const float* st = ws + WS_STAT + group * 6;
        float smean = st[0], sstd = st[1], wmean = st[2], wstd = st[3];
        bool az = st[4] != 0.0f;
        float v0, v1, v2;
        if (az) { v0 = i0; v1 = i1; v2 = i2; }
        else {
            v0 = ((i0 - wmean) / (wstd + 1e-8f)) * sstd + smean; v0 *= wmv;
            v1 = ((i1 - wmean) / (wstd + 1e-8f)) * sstd + smean; v1 *= wmv;
            v2 = ((i2 - wmean) / (wstd + 1e-8f)) * sstd + smean; v2 *= wmv;
        }
        o0 += v0; o1 += v1; o2 += v2; om += wmv;
    }
    float* base = out + ((size_t)b * 16 + ob * 4) * HWSZ;
    base[p] = o0;
    base[HWSZ + p] = o1;
    base[2 * HWSZ + p] = o2;
    base[3 * HWSZ + p] = om;
}

extern "C" void kernel_launch(void* const* d_in, const int* in_sizes, int n_in,
                              void* d_out, int out_size, void* d_ws, size_t ws_size,
                              hipStream_t stream)
{
    const float* prev  = (const float*)d_in[0];
    const float* org   = (const float*)d_in[1];
    const float* nxt   = (const float*)d_in[2];
    const float* maskT = (const float*)d_in[3];
    const float* K     = (const float*)d_in[4];
    const float* invK  = (const float*)d_in[5];
    const float* dep   = (const float*)d_in[6];
    const float* p2c   = (const float*)d_in[7];
    const float* c2n   = (const float*)d_in[8];
    const float* rel   = (const float*)d_in[9];
    const void*  camI  = d_in[10];
    const void*  nbr   = d_in[11];
    float* ws  = (float*)d_ws;
    float* out = (float*)d_out;

    size_t need = ((size_t)WS_CACHE + (size_t)12 * 4 * HWSZ) * sizeof(float);
    int use_cache = (ws_size >= need) ? 1 : 0;

    hipLaunchKernelGGL(vr_setup, dim3(1), dim3(128), 0, stream, K, invK, p2c, c2n, rel, camI, nbr, ws);
    hipLaunchKernelGGL(vr_phaseA, dim3(12 * BPG), dim3(256), 0, stream, prev, nxt, org, maskT, dep, ws, use_cache);
    hipLaunchKernelGGL(vr_finalize, dim3(1), dim3(64), 0, stream, ws);
    hipLaunchKernelGGL(vr_phaseB, dim3(4 * BB * HWSZ / 256), dim3(256), 0, stream, prev, nxt, maskT, dep, ws, out, use_cache);
}

// Round 3
// 76.258 us; speedup vs baseline: 1.3343x; 1.0291x over previous
//
#include <hip/hip_runtime.h>
#include <math.h>

#define HH 384
#define WW 640
#define HWSZ (HH*WW)
#define BB 2
#define NN 6
#define BPG 256   // blocks per (warp,batch) group in phaseA (12*BPG must be /8)

// ws layout (floats):
//  [0..143]    P matrices: (w*BB+b)*12  (3x4 row-major)
//  [144..161]  invK3 per b: 144 + b*9
//  [176..182]  cams (ints)
//  [192..287]  accumulators: 192 + (w*BB+b)*8 + k
//  [288..359]  stats: 288 + (w*BB+b)*6
//  [512..]     sample cache: (group*4 + c)*HWSZ + p
#define WS_P     0
#define WS_INVK  144
#define WS_CAM   176
#define WS_ACC   192
#define WS_STAT  288
#define WS_CACHE 512

// ---- projection, f32 op-order mirrored to the JAX reference, no FMA contraction ----
__device__ __forceinline__ void project_pix(const float* __restrict__ Pm, const float* __restrict__ ik,
                                            float fx, float fy, float d,
                                            float& gx, float& gy, float& sx, float& sy)
{
    float q0 = __fadd_rn(__fadd_rn(__fmul_rn(ik[0], fx), __fmul_rn(ik[1], fy)), ik[2]);
    float q1 = __fadd_rn(__fadd_rn(__fmul_rn(ik[3], fx), __fmul_rn(ik[4], fy)), ik[5]);
    float q2 = __fadd_rn(__fadd_rn(__fmul_rn(ik[6], fx), __fmul_rn(ik[7], fy)), ik[8]);
    float a0 = __fmul_rn(q0, d), a1 = __fmul_rn(q1, d), a2 = __fmul_rn(q2, d);
    float p0 = __fadd_rn(__fadd_rn(__fadd_rn(__fmul_rn(Pm[0], a0), __fmul_rn(Pm[1], a1)), __fmul_rn(Pm[2], a2)), Pm[3]);
    float p1 = __fadd_rn(__fadd_rn(__fadd_rn(__fmul_rn(Pm[4], a0), __fmul_rn(Pm[5], a1)), __fmul_rn(Pm[6], a2)), Pm[7]);
    float p2 = __fadd_rn(__fadd_rn(__fadd_rn(__fmul_rn(Pm[8], a0), __fmul_rn(Pm[9], a1)), __fmul_rn(Pm[10], a2)), Pm[11]);
    float z  = __fadd_rn(p2, 1e-7f);
    float xx = __fdiv_rn(p0, z);
    float yy = __fdiv_rn(p1, z);
    gx = __fmul_rn(__fsub_rn(__fdiv_rn(xx, 639.0f), 0.5f), 2.0f);
    gy = __fmul_rn(__fsub_rn(__fdiv_rn(yy, 383.0f), 0.5f), 2.0f);
    sx = __fmul_rn(__fmul_rn(__fadd_rn(gx, 1.0f), 0.5f), 639.0f);
    sy = __fmul_rn(__fmul_rn(__fadd_rn(gy, 1.0f), 0.5f), 383.0f);
}

// Predicated sampling: OOB taps issue NO memory transactions (result is 0
// regardless; 0*NaN divergence needs NaN in the input data, which is finite).
__device__ __forceinline__ void sample_one(const float* __restrict__ simg, const float* __restrict__ smask,
                                           const float* Pm, const float* ik, float d, int px_i, int py_i,
                                           float& i0, float& i1, float& i2, float& wmv)
{
    float gx, gy, sx, sy;
    project_pix(Pm, ik, (float)px_i, (float)py_i, d, gx, gy, sx, sy);

    float x0f = floorf(sx), y0f = floorf(sy);
    float wx = __fsub_rn(sx, x0f), wy = __fsub_rn(sy, y0f);
    int x0 = (int)x0f, y0 = (int)y0f;
    int x1 = x0 + 1, y1 = y0 + 1;
    bool vx0 = (x0 >= 0) && (x0 < WW), vx1 = (x1 >= 0) && (x1 < WW);
    bool vy0 = (y0 >= 0) && (y0 < HH), vy1 = (y1 >= 0) && (y1 < HH);
    int cx0 = min(max(x0, 0), WW - 1), cx1 = min(max(x1, 0), WW - 1);
    int cy0 = min(max(y0, 0), HH - 1), cy1 = min(max(y1, 0), HH - 1);
    float w00 = (1.0f - wx) * (1.0f - wy);
    float w01 = wx * (1.0f - wy);
    float w10 = (1.0f - wx) * wy;
    float w11 = wx * wy;
    int o00 = cy0 * WW + cx0, o01 = cy0 * WW + cx1;
    int o10 = cy1 * WW + cx0, o11 = cy1 * WW + cx1;
    float t00_0 = 0.f, t00_1 = 0.f, t00_2 = 0.f;
    float t01_0 = 0.f, t01_1 = 0.f, t01_2 = 0.f;
    float t10_0 = 0.f, t10_1 = 0.f, t10_2 = 0.f;
    float t11_0 = 0.f, t11_1 = 0.f, t11_2 = 0.f;
    if (vy0 && vx0) { t00_0 = simg[o00]; t00_1 = simg[HWSZ + o00]; t00_2 = simg[2 * HWSZ + o00]; }
    if (vy0 && vx1) { t01_0 = simg[o01]; t01_1 = simg[HWSZ + o01]; t01_2 = simg[2 * HWSZ + o01]; }
    if (vy1 && vx0) { t10_0 = simg[o10]; t10_1 = simg[HWSZ + o10]; t10_2 = simg[2 * HWSZ + o10]; }
    if (vy1 && vx1) { t11_0 = simg[o11]; t11_1 = simg[HWSZ + o11]; t11_2 = simg[2 * HWSZ + o11]; }
    float v0 = ((t00_0 * w00 + t01_0 * w01) + t10_0 * w10) + t11_0 * w11;
    float v1 = ((t00_1 * w00 + t01_1 * w01) + t10_1 * w10) + t11_1 * w11;
    float v2 = ((t00_2 * w00 + t01_2 * w01) + t10_2 * w10) + t11_2 * w11;
    i0 = (v0 != v0) ? 2.0f : v0;
    i1 = (v1 != v1) ? 2.0f : v1;
    i2 = (v2 != v2) ? 2.0f : v2;

    bool invalid = (gx > 1.0f) || (gx < -1.0f) || (gy > 1.0f) || (gy < -1.0f);
    float xr = rintf(sx), yr = rintf(sy);
    int xi = (int)xr, yi = (int)yr;
    bool vm = (xi >= 0) && (xi < WW) && (yi >= 0) && (yi < HH) && !invalid;
    float mv = 0.0f;
    if (vm) mv = smask[yi * WW + xi];
    if (mv != mv) mv = 0.0f;
    wmv = mv;
}

__global__ void vr_setup(const float* __restrict__ K, const float* __restrict__ invK,
                         const float* __restrict__ p2c, const float* __restrict__ c2n,
                         const float* __restrict__ rel, const void* __restrict__ camI,
                         const void* __restrict__ nbr, float* __restrict__ ws)
{
    int tid = threadIdx.x;
    if (tid < 96) ws[WS_ACC + tid] = 0.0f;
    if (tid == 0) {
        int ci = ((const int*)camI)[0];
        long long a = ((const long long*)nbr)[0];
        long long bq = ((const long long*)nbr)[1];
        int n0, n1;
        if (a >= 0 && a < NN && bq >= 0 && bq < NN) { n0 = (int)a; n1 = (int)bq; }
        else { n0 = ((const int*)nbr)[0]; n1 = ((const int*)nbr)[1]; }
        int* cams = (int*)(ws + WS_CAM);
        cams[0] = ci; cams[1] = ci; cams[2] = n0; cams[3] = n1; cams[4] = n0; cams[5] = n1;
        cams[6] = ci;
        for (int b = 0; b < BB; b++) {
            const float* ik = invK + (size_t)(b * NN + ci) * 16;
            float* dst = ws + WS_INVK + b * 9;
            dst[0] = ik[0]; dst[1] = ik[1]; dst[2] = ik[2];
            dst[3] = ik[4]; dst[4] = ik[5]; dst[5] = ik[6];
            dst[6] = ik[8]; dst[7] = ik[9]; dst[8] = ik[10];
            for (int w = 0; w < 6; w++) {
                int cam = cams[w];
                const float* Km = K + (size_t)(b * NN + cam) * 16;
                const float* T;
                if (w == 0)      T = p2c + (size_t)(b * NN + ci) * 16;
                else if (w == 1) T = c2n + (size_t)(b * NN + ci) * 16;
                else {
                    int f = (w >= 4) ? 1 : 0;
                    int n = (w == 3 || w == 5) ? 1 : 0;
                    T = rel + (size_t)((f * 2 + n) * BB + b) * 16;
                }
                float* Pd = ws + WS_P + (w * BB + b) * 12;
                for (int i = 0; i < 3; i++)
                    for (int j = 0; j < 4; j++) {
                        float s = __fadd_rn(__fadd_rn(__fadd_rn(
                                      __fmul_rn(Km[i * 4 + 0], T[0 * 4 + j]),
                                      __fmul_rn(Km[i * 4 + 1], T[1 * 4 + j])),
                                      __fmul_rn(Km[i * 4 + 2], T[2 * 4 + j])),
                                      __fmul_rn(Km[i * 4 + 3], T[3 * 4 + j]));
                        Pd[i * 4 + j] = s;
                    }
            }
        }
    }
}

__global__ __launch_bounds__(256) void vr_phaseA(
    const float* __restrict__ prev, const float* __restrict__ nxt,
    const float* __restrict__ org, const float* __restrict__ maskT,
    const float* __restrict__ depthT, float* __restrict__ ws, int use_cache)
{
    // XCD-pinned swizzle: blocks with the same blockIdx%8 (same XCD under
    // round-robin dispatch) process a contiguous chunk of groups, so each
    // XCD's L2 caches 1-2 source images instead of all 12.
    int xcd = blockIdx.x & 7;
    int v = xcd * (12 * BPG / 8) + (blockIdx.x >> 3);
    int group = v / BPG;              // 12 groups = (w, b)
    int blkin = v - group * BPG;
    int w = group / BB, b = group % BB;
    const int* cams = (const int*)(ws + WS_CAM);
    int ci = cams[6];
    int cam = cams[w];
    float Pl[12], ikl[9];
    {
        const float* Pm = ws + WS_P + group * 12;
        const float* ik = ws + WS_INVK + b * 9;
#pragma unroll
        for (int i = 0; i < 12; i++) Pl[i] = Pm[i];
#pragma unroll
        for (int i = 0; i < 9; i++) ikl[i] = ik[i];
    }
    const float* simg  = ((w == 0 || w == 2 || w == 3) ? prev : nxt) + (size_t)(b * NN + cam) * 3 * HWSZ;
    const float* smask = maskT + (size_t)(b * NN + cam) * HWSZ;
    const float* dep   = depthT + (size_t)(b * NN + ci) * HWSZ;
    const float* rimg  = org + (size_t)(b * NN + ci) * 3 * HWSZ;
    const float* rmask = maskT + (size_t)(b * NN + ci) * HWSZ;
    float* cache = ws + WS_CACHE + (size_t)group * 4 * HWSZ;

    float acc[7] = {0, 0, 0, 0, 0, 0, 0};
    for (int p = blkin * 256 + threadIdx.x; p < HWSZ; p += BPG * 256) {
        int py_i = p / WW, px_i = p - py_i * WW;
        float d = dep[p];
        float i0, i1, i2, wmv;
        sample_one(simg, smask, Pl, ikl, d, px_i, py_i, i0, i1, i2, wmv);
        if (use_cache) {
            cache[p] = i0;
            cache[HWSZ + p] = i1;
            cache[2 * HWSZ + p] = i2;
            cache[3 * HWSZ + p] = wmv;
        }
        float rm = rmask[p];
        float m = (rm * wmv > 0.0f) ? 1.0f : 0.0f;
        float r0 = rimg[p], r1 = rimg[HWSZ + p], r2 = rimg[2 * HWSZ + p];
        float ws3 = i0 + i1 + i2;
        float rs3 = r0 + r1 + r2;
        acc[0] += m;
        acc[1] += rs3 * m;
        acc[2] += ws3 * m;
        acc[3] += ws3;
        acc[4] += i0 * i0 + i1 * i1 + i2 * i2;
        acc[5] += rs3;
        acc[6] += r0 * r0 + r1 * r1 + r2 * r2;
    }
    __shared__ float sred[4][7];
    int lane = threadIdx.x & 63, wv = threadIdx.x >> 6;
#pragma unroll
    for (int k = 0; k < 7; k++) {
        float v2 = acc[k];
        for (int off = 32; off; off >>= 1) v2 += __shfl_down(v2, off);
        if (lane == 0) sred[wv][k] = v2;
    }
    __syncthreads();
    if (threadIdx.x < 7) {
        float s = sred[0][threadIdx.x] + sred[1][threadIdx.x] + sred[2][threadIdx.x] + sred[3][threadIdx.x];
        atomicAdd(&ws[WS_ACC + group * 8 + threadIdx.x], s);
    }
}

__global__ void vr_finalize(float* __restrict__ ws)
{
    int t = threadIdx.x;
    if (t >= 12) return;
    int w = t / BB;
    const float* acc = ws + WS_ACC + t * 8;
    double cnt = acc[0], smask = acc[1], wmask = acc[2];
    double wsum = acc[3], wsumsq = acc[4], ssum = acc[5], ssumsq = acc[6];
    double msum = 3.0 * cnt;
    double NT = 3.0 * (double)HWSZ;
    double smean = smask / (msum + 1e-8);
    double svar  = (ssumsq - 2.0 * smean * ssum + NT * smean * smean) / NT;
    double sstd  = sqrt(svar + 1e-16);
    double wmean = wmask / (msum + 1e-8);
    double wvar  = (wsumsq - 2.0 * wmean * wsum + NT * wmean * wmean) / NT;
    double wstd  = sqrt(wvar + 1e-16);
    float cnt0 = ws[WS_ACC + (w * BB + 0) * 8];
    float cnt1 = ws[WS_ACC + (w * BB + 1) * 8];
    float az = (cnt0 == 0.0f || cnt1 == 0.0f) ? 1.0f : 0.0f;
    float* st = ws + WS_STAT + t * 6;
    st[0] = (float)smean; st[1] = (float)sstd;
    st[2] = (float)wmean; st[3] = (float)wstd;
    st[4] = az;
}

__global__ __launch_bounds__(256) void vr_phaseB(
    const float* __restrict__ prev, const float* __restrict__ nxt,
    const float* __restrict__ maskT, const float* __restrict__ depthT,
    const float* __restrict__ ws, float* __restrict__ out, int use_cache)
{
    int idx = blockIdx.x * 256 + threadIdx.x;
    int ob = idx / (BB * HWSZ);
    int rem = idx - ob * (BB * HWSZ);
    int b = rem / HWSZ;
    int p = rem - b * HWSZ;
    const int* cams = (const int*)(ws + WS_CAM);
    int ci = cams[6];
    int py_i = p / WW, px_i = p - py_i * WW;
    int w0 = (ob == 0) ? 0 : (ob == 1) ? 1 : (ob == 2) ? 2 : 4;
    int nw = (ob < 2) ? 1 : 2;
    float o0 = 0, o1 = 0, o2 = 0, om = 0;
    for (int k = 0; k < nw; k++) {
        int w = w0 + k;
        int group = w * BB + b;
        float i0, i1, i2, wmv;
        if (use_cache) {
            const float* cg = ws + WS_CACHE + (size_t)group * 4 * HWSZ;
            i0 = cg[p]; i1 = cg[HWSZ + p]; i2 = cg[2 * HWSZ + p]; wmv = cg[3 * HWSZ + p];
        } else {
            int cam = cams[w];
            const float* Pm = ws + WS_P + group * 12;
            const float* ik = ws + WS_INVK + b * 9;
            const float* simg  = ((w == 0 || w == 2 || w == 3) ? prev : nxt) + (size_t)(b * NN + cam) * 3 * HWSZ;
            const float* smask = maskT + (size_t)(b * NN + cam) * HWSZ;
            float d = depthT[(size_t)(b * NN + ci) * HWSZ + p];
            sample_one(simg, smask, Pm, ik, d, px_i, py_i, i0, i1, i2, wmv);
        }
        const float* st = ws + WS_STAT + group * 6;
        float smean = st[0], sstd = st[1], wmean = st[2], wstd = st[3];
        bool az = st[4] != 0.0f;
        float v0, v1, v2;
        if (az) { v0 = i0; v1 = i1; v2 = i2; }
        else {
            v0 = ((i0 - wmean) / (wstd + 1e-8f)) * sstd + smean; v0 *= wmv;
            v1 = ((i1 - wmean) / (wstd + 1e-8f)) * sstd + smean; v1 *= wmv;
            v2 = ((i2 - wmean) / (wstd + 1e-8f)) * sstd + smean; v2 *= wmv;
        }
        o0 += v0; o1 += v1; o2 += v2; om += wmv;
    }
    float* base = out + ((size_t)b * 16 + ob * 4) * HWSZ;
    base[p] = o0;
    base[HWSZ + p] = o1;
    base[2 * HWSZ + p] = o2;
    base[3 * HWSZ + p] = om;
}

extern "C" void kernel_launch(void* const* d_in, const int* in_sizes, int n_in,
                              void* d_out, int out_size, void* d_ws, size_t ws_size,
                              hipStream_t stream)
{
    const float* prev  = (const float*)d_in[0];
    const float* org   = (const float*)d_in[1];
    const float* nxt   = (const float*)d_in[2];
    const float* maskT = (const float*)d_in[3];
    const float* K     = (const float*)d_in[4];
    const float* invK  = (const float*)d_in[5];
    const float* dep   = (const float*)d_in[6];
    const float* p2c   = (const float*)d_in[7];
    const float* c2n   = (const float*)d_in[8];
    const float* rel   = (const float*)d_in[9];
    const void*  camI  = d_in[10];
    const void*  nbr   = d_in[11];
    float* ws  = (float*)d_ws;
    float* out = (float*)d_out;

    size_t need = ((size_t)WS_CACHE + (size_t)12 * 4 * HWSZ) * sizeof(float);
    int use_cache = (ws_size >= need) ? 1 : 0;

    hipLaunchKernelGGL(vr_setup, dim3(1), dim3(128), 0, stream, K, invK, p2c, c2n, rel, camI, nbr, ws);
    hipLaunchKernelGGL(vr_phaseA, dim3(12 * BPG), dim3(256), 0, stream, prev, nxt, org, maskT, dep, ws, use_cache);
    hipLaunchKernelGGL(vr_finalize, dim3(1), dim3(64), 0, stream, ws);
    hipLaunchKernelGGL(vr_phaseB, dim3(4 * BB * HWSZ / 256), dim3(256), 0, stream, prev, nxt, maskT, dep, ws, out, use_cache);
}

// Round 4
// 66.783 us; speedup vs baseline: 1.5236x; 1.1419x over previous
//
#include <hip/hip_runtime.h>
#include <hip/hip_fp16.h>
#include <math.h>

#define HH 384
#define WW 640
#define HWSZ (HH*WW)
#define BB 2
#define NN 6
#define BPG 256   // blocks per (warp,batch) group in phaseA

// ws layout (floats):
//  [0..143]    P matrices: (w*BB+b)*12  (3x4 row-major)
//  [144..161]  invK3 per b: 144 + b*9
//  [176..182]  cams (ints)
//  [192..287]  accumulators: 192 + (w*BB+b)*8 + k
//  [288..359]  stats: 288 + (w*BB+b)*6
//  [512..]                 packed src RGBM half4: (group*HWSZ + p) uint2
//  [512+12*HWSZ*2 ..]      sample cache half4:    (group*HWSZ + p) uint2
#define WS_P      0
#define WS_INVK   144
#define WS_CAM    176
#define WS_ACC    192
#define WS_STAT   288
#define WS_PACK   512
#define WS_CACHE2 (512 + 12 * HWSZ * 2)
#define WS_END    (WS_CACHE2 + 12 * HWSZ * 2)

__device__ __forceinline__ unsigned pack2(float a, float b) {
    __half2 h = __halves2half2(__float2half(a), __float2half(b));
    union { __half2 h2; unsigned u; } cv; cv.h2 = h; return cv.u;
}
__device__ __forceinline__ float2 unpack2(unsigned u) {
    union { __half2 h2; unsigned u; } cv; cv.u = u;
    return __half22float2(cv.h2);
}

// ---- projection, f32 op-order mirrored to the JAX reference, no FMA contraction ----
__device__ __forceinline__ void project_pix(const float* __restrict__ Pm, const float* __restrict__ ik,
                                            float fx, float fy, float d,
                                            float& gx, float& gy, float& sx, float& sy)
{
    float q0 = __fadd_rn(__fadd_rn(__fmul_rn(ik[0], fx), __fmul_rn(ik[1], fy)), ik[2]);
    float q1 = __fadd_rn(__fadd_rn(__fmul_rn(ik[3], fx), __fmul_rn(ik[4], fy)), ik[5]);
    float q2 = __fadd_rn(__fadd_rn(__fmul_rn(ik[6], fx), __fmul_rn(ik[7], fy)), ik[8]);
    float a0 = __fmul_rn(q0, d), a1 = __fmul_rn(q1, d), a2 = __fmul_rn(q2, d);
    float p0 = __fadd_rn(__fadd_rn(__fadd_rn(__fmul_rn(Pm[0], a0), __fmul_rn(Pm[1], a1)), __fmul_rn(Pm[2], a2)), Pm[3]);
    float p1 = __fadd_rn(__fadd_rn(__fadd_rn(__fmul_rn(Pm[4], a0), __fmul_rn(Pm[5], a1)), __fmul_rn(Pm[6], a2)), Pm[7]);
    float p2 = __fadd_rn(__fadd_rn(__fadd_rn(__fmul_rn(Pm[8], a0), __fmul_rn(Pm[9], a1)), __fmul_rn(Pm[10], a2)), Pm[11]);
    float z  = __fadd_rn(p2, 1e-7f);
    float xx = __fdiv_rn(p0, z);
    float yy = __fdiv_rn(p1, z);
    gx = __fmul_rn(__fsub_rn(__fdiv_rn(xx, 639.0f), 0.5f), 2.0f);
    gy = __fmul_rn(__fsub_rn(__fdiv_rn(yy, 383.0f), 0.5f), 2.0f);
    sx = __fmul_rn(__fmul_rn(__fadd_rn(gx, 1.0f), 0.5f), 639.0f);
    sy = __fmul_rn(__fmul_rn(__fadd_rn(gy, 1.0f), 0.5f), 383.0f);
}

// Packed-texel sampler: 4 predicated 8B taps; mask tap selected from a corner.
__device__ __forceinline__ void sample_packed(const uint2* __restrict__ pk,
                                              const float* Pm, const float* ik, float d, int px_i, int py_i,
                                              float& i0, float& i1, float& i2, float& wmv)
{
    float gx, gy, sx, sy;
    project_pix(Pm, ik, (float)px_i, (float)py_i, d, gx, gy, sx, sy);

    float x0f = floorf(sx), y0f = floorf(sy);
    float wx = __fsub_rn(sx, x0f), wy = __fsub_rn(sy, y0f);
    int x0 = (int)x0f, y0 = (int)y0f;
    int x1 = x0 + 1, y1 = y0 + 1;
    bool vx0 = (x0 >= 0) && (x0 < WW), vx1 = (x1 >= 0) && (x1 < WW);
    bool vy0 = (y0 >= 0) && (y0 < HH), vy1 = (y1 >= 0) && (y1 < HH);
    float w00 = (1.0f - wx) * (1.0f - wy);
    float w01 = wx * (1.0f - wy);
    float w10 = (1.0f - wx) * wy;
    float w11 = wx * wy;
    uint2 t00 = {0u, 0u}, t01 = {0u, 0u}, t10 = {0u, 0u}, t11 = {0u, 0u};
    if (vy0 && vx0) t00 = pk[y0 * WW + x0];
    if (vy0 && vx1) t01 = pk[y0 * WW + x1];
    if (vy1 && vx0) t10 = pk[y1 * WW + x0];
    if (vy1 && vx1) t11 = pk[y1 * WW + x1];
    float2 a00 = unpack2(t00.x), b00 = unpack2(t00.y);
    float2 a01 = unpack2(t01.x), b01 = unpack2(t01.y);
    float2 a10 = unpack2(t10.x), b10 = unpack2(t10.y);
    float2 a11 = unpack2(t11.x), b11 = unpack2(t11.y);
    float v0 = ((a00.x * w00 + a01.x * w01) + a10.x * w10) + a11.x * w11;
    float v1 = ((a00.y * w00 + a01.y * w01) + a10.y * w10) + a11.y * w11;
    float v2 = ((b00.x * w00 + b01.x * w01) + b10.x * w10) + b11.x * w11;
    i0 = (v0 != v0) ? 2.0f : v0;
    i1 = (v1 != v1) ? 2.0f : v1;
    i2 = (v2 != v2) ? 2.0f : v2;

    bool invalid = (gx > 1.0f) || (gx < -1.0f) || (gy > 1.0f) || (gy < -1.0f);
    float xr = rintf(sx), yr = rintf(sy);
    int xi = (int)xr, yi = (int)yr;
    bool vm = (xi >= 0) && (xi < WW) && (yi >= 0) && (yi < HH) && !invalid;
    bool selx = (xi == x1), sely = (yi == y1);
    float m00 = b00.y, m01 = b01.y, m10 = b10.y, m11 = b11.y;
    float msel = sely ? (selx ? m11 : m10) : (selx ? m01 : m00);
    float mv = vm ? msel : 0.0f;
    if (mv != mv) mv = 0.0f;
    wmv = mv;
}

// Planar fallback sampler (used only if ws is too small for the packed buffers).
__device__ __forceinline__ void sample_one(const float* __restrict__ simg, const float* __restrict__ smask,
                                           const float* Pm, const float* ik, float d, int px_i, int py_i,
                                           float& i0, float& i1, float& i2, float& wmv)
{
    float gx, gy, sx, sy;
    project_pix(Pm, ik, (float)px_i, (float)py_i, d, gx, gy, sx, sy);
    float x0f = floorf(sx), y0f = floorf(sy);
    float wx = __fsub_rn(sx, x0f), wy = __fsub_rn(sy, y0f);
    int x0 = (int)x0f, y0 = (int)y0f;
    int x1 = x0 + 1, y1 = y0 + 1;
    bool vx0 = (x0 >= 0) && (x0 < WW), vx1 = (x1 >= 0) && (x1 < WW);
    bool vy0 = (y0 >= 0) && (y0 < HH), vy1 = (y1 >= 0) && (y1 < HH);
    float w00 = (1.0f - wx) * (1.0f - wy);
    float w01 = wx * (1.0f - wy);
    float w10 = (1.0f - wx) * wy;
    float w11 = wx * wy;
    int o00 = y0 * WW + x0, o01 = y0 * WW + x1;
    int o10 = y1 * WW + x0, o11 = y1 * WW + x1;
    float t00_0 = 0.f, t00_1 = 0.f, t00_2 = 0.f;
    float t01_0 = 0.f, t01_1 = 0.f, t01_2 = 0.f;
    float t10_0 = 0.f, t10_1 = 0.f, t10_2 = 0.f;
    float t11_0 = 0.f, t11_1 = 0.f, t11_2 = 0.f;
    if (vy0 && vx0) { t00_0 = simg[o00]; t00_1 = simg[HWSZ + o00]; t00_2 = simg[2 * HWSZ + o00]; }
    if (vy0 && vx1) { t01_0 = simg[o01]; t01_1 = simg[HWSZ + o01]; t01_2 = simg[2 * HWSZ + o01]; }
    if (vy1 && vx0) { t10_0 = simg[o10]; t10_1 = simg[HWSZ + o10]; t10_2 = simg[2 * HWSZ + o10]; }
    if (vy1 && vx1) { t11_0 = simg[o11]; t11_1 = simg[HWSZ + o11]; t11_2 = simg[2 * HWSZ + o11]; }
    float v0 = ((t00_0 * w00 + t01_0 * w01) + t10_0 * w10) + t11_0 * w11;
    float v1 = ((t00_1 * w00 + t01_1 * w01) + t10_1 * w10) + t11_1 * w11;
    float v2 = ((t00_2 * w00 + t01_2 * w01) + t10_2 * w10) + t11_2 * w11;
    i0 = (v0 != v0) ? 2.0f : v0;
    i1 = (v1 != v1) ? 2.0f : v1;
    i2 = (v2 != v2) ? 2.0f : v2;
    bool invalid = (gx > 1.0f) || (gx < -1.0f) || (gy > 1.0f) || (gy < -1.0f);
    float xr = rintf(sx), yr = rintf(sy);
    int xi = (int)xr, yi = (int)yr;
    bool vm = (xi >= 0) && (xi < WW) && (yi >= 0) && (yi < HH) && !invalid;
    float mv = 0.0f;
    if (vm) mv = smask[yi * WW + xi];
    if (mv != mv) mv = 0.0f;
    wmv = mv;
}

__global__ void vr_setup(const float* __restrict__ K, const float* __restrict__ invK,
                         const float* __restrict__ p2c, const float* __restrict__ c2n,
                         const float* __restrict__ rel, const void* __restrict__ camI,
                         const void* __restrict__ nbr, float* __restrict__ ws)
{
    int tid = threadIdx.x;
    if (tid < 96) ws[WS_ACC + tid] = 0.0f;
    if (tid == 0) {
        int ci = ((const int*)camI)[0];
        long long a = ((const long long*)nbr)[0];
        long long bq = ((const long long*)nbr)[1];
        int n0, n1;
        if (a >= 0 && a < NN && bq >= 0 && bq < NN) { n0 = (int)a; n1 = (int)bq; }
        else { n0 = ((const int*)nbr)[0]; n1 = ((const int*)nbr)[1]; }
        int* cams = (int*)(ws + WS_CAM);
        cams[0] = ci; cams[1] = ci; cams[2] = n0; cams[3] = n1; cams[4] = n0; cams[5] = n1;
        cams[6] = ci;
        for (int b = 0; b < BB; b++) {
            const float* ik = invK + (size_t)(b * NN + ci) * 16;
            float* dst = ws + WS_INVK + b * 9;
            dst[0] = ik[0]; dst[1] = ik[1]; dst[2] = ik[2];
            dst[3] = ik[4]; dst[4] = ik[5]; dst[5] = ik[6];
            dst[6] = ik[8]; dst[7] = ik[9]; dst[8] = ik[10];
            for (int w = 0; w < 6; w++) {
                int cam = cams[w];
                const float* Km = K + (size_t)(b * NN + cam) * 16;
                const float* T;
                if (w == 0)      T = p2c + (size_t)(b * NN + ci) * 16;
                else if (w == 1) T = c2n + (size_t)(b * NN + ci) * 16;
                else {
                    int f = (w >= 4) ? 1 : 0;
                    int n = (w == 3 || w == 5) ? 1 : 0;
                    T = rel + (size_t)((f * 2 + n) * BB + b) * 16;
                }
                float* Pd = ws + WS_P + (w * BB + b) * 12;
                for (int i = 0; i < 3; i++)
                    for (int j = 0; j < 4; j++) {
                        float s = __fadd_rn(__fadd_rn(__fadd_rn(
                                      __fmul_rn(Km[i * 4 + 0], T[0 * 4 + j]),
                                      __fmul_rn(Km[i * 4 + 1], T[1 * 4 + j])),
                                      __fmul_rn(Km[i * 4 + 2], T[2 * 4 + j])),
                                      __fmul_rn(Km[i * 4 + 3], T[3 * 4 + j]));
                        Pd[i * 4 + j] = s;
                    }
            }
        }
    }
}

// Pack each group's source image RGB + mask into half4 texels (8B).
__global__ __launch_bounds__(256) void vr_pack(
    const float* __restrict__ prev, const float* __restrict__ nxt,
    const float* __restrict__ maskT, float* __restrict__ ws)
{
    int gid = blockIdx.x * 256 + threadIdx.x;
    int group = gid / HWSZ;
    int p = gid - group * HWSZ;
    int w = group / BB, b = group % BB;
    const int* cams = (const int*)(ws + WS_CAM);
    int cam = cams[w];
    const float* simg  = ((w == 0 || w == 2 || w == 3) ? prev : nxt) + (size_t)(b * NN + cam) * 3 * HWSZ;
    const float* smask = maskT + (size_t)(b * NN + cam) * HWSZ;
    float r = simg[p], g = simg[HWSZ + p], bl = simg[2 * HWSZ + p], m = smask[p];
    uint2 u;
    u.x = pack2(r, g);
    u.y = pack2(bl, m);
    ((uint2*)(ws + WS_PACK))[(size_t)group * HWSZ + p] = u;
}

__global__ __launch_bounds__(256) void vr_phaseA(
    const float* __restrict__ prev, const float* __restrict__ nxt,
    const float* __restrict__ org, const float* __restrict__ maskT,
    const float* __restrict__ depthT, float* __restrict__ ws, int mode)
{
    int group = blockIdx.x / BPG;     // natural order: round-robin mixes heavy/light groups
    int blkin = blockIdx.x % BPG;
    int w = group / BB, b = group % BB;
    const int* cams = (const int*)(ws + WS_CAM);
    int ci = cams[6];
    int cam = cams[w];
    float Pl[12], ikl[9];
    {
        const float* Pm = ws + WS_P + group * 12;
        const float* ik = ws + WS_INVK + b * 9;
#pragma unroll
        for (int i = 0; i < 12; i++) Pl[i] = Pm[i];
#pragma unroll
        for (int i = 0; i < 9; i++) ikl[i] = ik[i];
    }
    const float* simg  = ((w == 0 || w == 2 || w == 3) ? prev : nxt) + (size_t)(b * NN + cam) * 3 * HWSZ;
    const float* smask = maskT + (size_t)(b * NN + cam) * HWSZ;
    const float* dep   = depthT + (size_t)(b * NN + ci) * HWSZ;
    const float* rimg  = org + (size_t)(b * NN + ci) * 3 * HWSZ;
    const float* rmask = maskT + (size_t)(b * NN + ci) * HWSZ;
    const uint2* pk  = (const uint2*)(ws + WS_PACK) + (size_t)group * HWSZ;
    uint2* cache     = (uint2*)(ws + WS_CACHE2) + (size_t)group * HWSZ;

    float acc[7] = {0, 0, 0, 0, 0, 0, 0};
    for (int p = blkin * 256 + threadIdx.x; p < HWSZ; p += BPG * 256) {
        int py_i = p / WW, px_i = p - py_i * WW;
        float d = dep[p];
        float i0, i1, i2, wmv;
        if (mode) {
            sample_packed(pk, Pl, ikl, d, px_i, py_i, i0, i1, i2, wmv);
            uint2 u; u.x = pack2(i0, i1); u.y = pack2(i2, wmv);
            cache[p] = u;
        } else {
            sample_one(simg, smask, Pl, ikl, d, px_i, py_i, i0, i1, i2, wmv);
        }
        float rm = rmask[p];
        float m = (rm * wmv > 0.0f) ? 1.0f : 0.0f;
        float r0 = rimg[p], r1 = rimg[HWSZ + p], r2 = rimg[2 * HWSZ + p];
        float ws3 = i0 + i1 + i2;
        float rs3 = r0 + r1 + r2;
        acc[0] += m;
        acc[1] += rs3 * m;
        acc[2] += ws3 * m;
        acc[3] += ws3;
        acc[4] += i0 * i0 + i1 * i1 + i2 * i2;
        acc[5] += rs3;
        acc[6] += r0 * r0 + r1 * r1 + r2 * r2;
    }
    __shared__ float sred[4][7];
    int lane = threadIdx.x & 63, wv = threadIdx.x >> 6;
#pragma unroll
    for (int k = 0; k < 7; k++) {
        float v2 = acc[k];
        for (int off = 32; off; off >>= 1) v2 += __shfl_down(v2, off);
        if (lane == 0) sred[wv][k] = v2;
    }
    __syncthreads();
    if (threadIdx.x < 7) {
        float s = sred[0][threadIdx.x] + sred[1][threadIdx.x] + sred[2][threadIdx.x] + sred[3][threadIdx.x];
        atomicAdd(&ws[WS_ACC + group * 8 + threadIdx.x], s);
    }
}

__global__ void vr_finalize(float* __restrict__ ws)
{
    int t = threadIdx.x;
    if (t >= 12) return;
    int w = t / BB;
    const float* acc = ws + WS_ACC + t * 8;
    double cnt = acc[0], smask = acc[1], wmask = acc[2];
    double wsum = acc[3], wsumsq = acc[4], ssum = acc[5], ssumsq = acc[6];
    double msum = 3.0 * cnt;
    double NT = 3.0 * (double)HWSZ;
    double smean = smask / (msum + 1e-8);
    double svar  = (ssumsq - 2.0 * smean * ssum + NT * smean * smean) / NT;
    double sstd  = sqrt(svar + 1e-16);
    double wmean = wmask / (msum + 1e-8);
    double wvar  = (wsumsq - 2.0 * wmean * wsum + NT * wmean * wmean) / NT;
    double wstd  = sqrt(wvar + 1e-16);
    float cnt0 = ws[WS_ACC + (w * BB + 0) * 8];
    float cnt1 = ws[WS_ACC + (w * BB + 1) * 8];
    float az = (cnt0 == 0.0f || cnt1 == 0.0f) ? 1.0f : 0.0f;
    float* st = ws + WS_STAT + t * 6;
    st[0] = (float)smean; st[1] = (float)sstd;
    st[2] = (float)wmean; st[3] = (float)wstd;
    st[4] = az;
}

__global__ __launch_bounds__(256) void vr_phaseB(
    const float* __restrict__ prev, const float* __restrict__ nxt,
    const float* __restrict__ maskT, const float* __restrict__ depthT,
    const float* __restrict__ ws, float* __restrict__ out, int mode)
{
    int idx = blockIdx.x * 256 + threadIdx.x;
    int ob = idx / (BB * HWSZ);
    int rem = idx - ob * (BB * HWSZ);
    int b = rem / HWSZ;
    int p = rem - b * HWSZ;
    const int* cams = (const int*)(ws + WS_CAM);
    int ci = cams[6];
    int py_i = p / WW, px_i = p - py_i * WW;
    int w0 = (ob == 0) ? 0 : (ob == 1) ? 1 : (ob == 2) ? 2 : 4;
    int nw = (ob < 2) ? 1 : 2;
    float o0 = 0, o1 = 0, o2 = 0, om = 0;
    for (int k = 0; k < nw; k++) {
        int w = w0 + k;
        int group = w * BB + b;
        float i0, i1, i2, wmv;
        if (mode) {
            const uint2* cg = (const uint2*)(ws + WS_CACHE2) + (size_t)group * HWSZ;
            uint2 u = cg[p];
            float2 ab = unpack2(u.x), cd = unpack2(u.y);
            i0 = ab.x; i1 = ab.y; i2 = cd.x; wmv = cd.y;
        } else {
            int cam = cams[w];
            const float* Pm = ws + WS_P + group * 12;
            const float* ik = ws + WS_INVK + b * 9;
            const float* simg  = ((w == 0 || w == 2 || w == 3) ? prev : nxt) + (size_t)(b * NN + cam) * 3 * HWSZ;
            const float* smask = maskT + (size_t)(b * NN + cam) * HWSZ;
            float d = depthT[(size_t)(b * NN + ci) * HWSZ + p];
            sample_one(simg, smask, Pm, ik, d, px_i, py_i, i0, i1, i2, wmv);
        }
        const float* st = ws + WS_STAT + group * 6;
        float smean = st[0], sstd = st[1], wmean = st[2], wstd = st[3];
        bool az = st[4] != 0.0f;
        float v0, v1, v2;
        if (az) { v0 = i0; v1 = i1; v2 = i2; }
        else {
            v0 = ((i0 - wmean) / (wstd + 1e-8f)) * sstd + smean; v0 *= wmv;
            v1 = ((i1 - wmean) / (wstd + 1e-8f)) * sstd + smean; v1 *= wmv;
            v2 = ((i2 - wmean) / (wstd + 1e-8f)) * sstd + smean; v2 *= wmv;
        }
        o0 += v0; o1 += v1; o2 += v2; om += wmv;
    }
    float* base = out + ((size_t)b * 16 + ob * 4) * HWSZ;
    base[p] = o0;
    base[HWSZ + p] = o1;
    base[2 * HWSZ + p] = o2;
    base[3 * HWSZ + p] = om;
}

extern "C" void kernel_launch(void* const* d_in, const int* in_sizes, int n_in,
                              void* d_out, int out_size, void* d_ws, size_t ws_size,
                              hipStream_t stream)
{
    const float* prev  = (const float*)d_in[0];
    const float* org   = (const float*)d_in[1];
    const float* nxt   = (const float*)d_in[2];
    const float* maskT = (const float*)d_in[3];
    const float* K     = (const float*)d_in[4];
    const float* invK  = (const float*)d_in[5];
    const float* dep   = (const float*)d_in[6];
    const float* p2c   = (const float*)d_in[7];
    const float* c2n   = (const float*)d_in[8];
    const float* rel   = (const float*)d_in[9];
    const void*  camI  = d_in[10];
    const void*  nbr   = d_in[11];
    float* ws  = (float*)d_ws;
    float* out = (float*)d_out;

    size_t need = (size_t)WS_END * sizeof(float);
    int mode = (ws_size >= need) ? 1 : 0;

    hipLaunchKernelGGL(vr_setup, dim3(1), dim3(128), 0, stream, K, invK, p2c, c2n, rel, camI, nbr, ws);
    if (mode)
        hipLaunchKernelGGL(vr_pack, dim3(12 * HWSZ / 256), dim3(256), 0, stream, prev, nxt, maskT, ws);
    hipLaunchKernelGGL(vr_phaseA, dim3(12 * BPG), dim3(256), 0, stream, prev, nxt, org, maskT, dep, ws, mode);
    hipLaunchKernelGGL(vr_finalize, dim3(1), dim3(64), 0, stream, ws);
    hipLaunchKernelGGL(vr_phaseB, dim3(4 * BB * HWSZ / 256), dim3(256), 0, stream, prev, nxt, maskT, dep, ws, out, mode);
}